// Round 4
// baseline (2358.453 us; speedup 1.0000x reference)
//
#include <hip/hip_runtime.h>

#define NS_TOT 2000
#define NA 1000
#define NI 5
#define NH 32

// tanh(x) = 1 - 2/(exp(2x)+1). Saturates correctly; ~1e-6 abs err.
__device__ __forceinline__ float fast_tanh(float x) {
    float E = __expf(2.0f * x);
    float r = __builtin_amdgcn_rcpf(E + 1.0f);
    return fmaf(-2.0f, r, 1.0f);
}

// value-semantics fma: acc += s * w  (componentwise)
__device__ __forceinline__ float4 ffma4(float s, float4 w, float4 acc) {
    acc.x = fmaf(s, w.x, acc.x);
    acc.y = fmaf(s, w.y, acc.y);
    acc.z = fmaf(s, w.z, acc.z);
    acc.w = fmaf(s, w.w, acc.w);
    return acc;
}

#define TANH4(v) { (v).x = fast_tanh((v).x); (v).y = fast_tanh((v).y); \
                   (v).z = fast_tanh((v).z); (v).w = fast_tanh((v).w); }

// R2/R3 lesson: pragma-unrolled loops over h[]/c[] were NOT fully unrolled by
// the compiler -> runtime indices -> allocas stayed in scratch -> GBs of HBM
// spill traffic (R3: VGPR_Count=64, FETCH=1.1GB). Macro-expansion below makes
// every array subscript a literal constant so SROA must promote to registers.

__global__ __launch_bounds__(256, 2) void mlp_per_atom(
    const float* __restrict__ g,
    const float* __restrict__ W1, const float* __restrict__ b1,
    const float* __restrict__ W2, const float* __restrict__ b2,
    const float* __restrict__ W3, const float* __restrict__ b3,
    float* __restrict__ out)
{
    // XCD swizzle: 16 consecutive atoms share a 64B line of g/out; map
    // consecutive atoms to the SAME XCD (bid%8 is the XCD on MI355X) so the
    // line is assembled in one L2 instead of 8 partial-line HBM writes.
    const int bid = blockIdx.x;
    const int a = (bid >> 3) + 125 * (bid & 7);   // NA=1000 = 8*125
    const int t = threadIdx.x;

    __shared__ __align__(16) float sW1[NI * NH];
    __shared__ __align__(16) float sB1[NH];
    __shared__ __align__(16) float sW2[NH * NH];
    __shared__ __align__(16) float sB2[NH];
    __shared__ __align__(16) float sW3[NH];
    __shared__ float sB3;

    for (int i = t; i < NI * NH; i += 256) sW1[i] = W1[a * NI * NH + i];
    for (int i = t; i < NH * NH; i += 256) sW2[i] = W2[a * NH * NH + i];
    if (t < NH) {
        sB1[t] = b1[a * NH + t];
        sB2[t] = b2[a * NH + t];
        sW3[t] = W3[a * NH + t];
    }
    if (t == 0) sB3 = b3[a];
    __syncthreads();

    const float4* w1v = (const float4*)sW1;
    const float4* b1v = (const float4*)sB1;
    const float4* w2v = (const float4*)sW2;
    const float4* b2v = (const float4*)sB2;
    const float4* w3v = (const float4*)sW3;
    const float bias3 = sB3;

    // 2 structs per thread per iteration: each ds_read_b128 of weights feeds
    // 8 FMAs (VALU-bound), instead of 4 (DS-bound).
    for (int s0 = t; s0 < NS_TOT; s0 += 512) {
        const int s1 = s0 + 256;
        const bool v1 = (s1 < NS_TOT);
        const int s1c = v1 ? s1 : s0;   // clamp: duplicate work, store skipped

        const float* gp0 = g + ((size_t)s0  * NA + a) * NI;
        const float* gp1 = g + ((size_t)s1c * NA + a) * NI;
        const float ga0 = gp0[0], ga1 = gp0[1], ga2 = gp0[2], ga3 = gp0[3], ga4 = gp0[4];
        const float gb0 = gp1[0], gb1 = gp1[1], gb2 = gp1[2], gb3 = gp1[3], gb4 = gp1[4];

        // ---- layer 1: 5 -> 32 ----
        float4 h0[8], h1[8];
        #define INITH(q) { float4 b = b1v[q]; h0[q] = b; h1[q] = b; }
        INITH(0) INITH(1) INITH(2) INITH(3) INITH(4) INITH(5) INITH(6) INITH(7)
        #undef INITH

        #define L1Q(i, q) { float4 w = w1v[(i) * 8 + (q)]; \
            h0[q] = ffma4(x0, w, h0[q]); h1[q] = ffma4(x1, w, h1[q]); }
        #define L1I(i) { const float x0 = ga##i; const float x1 = gb##i; \
            L1Q(i,0) L1Q(i,1) L1Q(i,2) L1Q(i,3) L1Q(i,4) L1Q(i,5) L1Q(i,6) L1Q(i,7) }
        L1I(0) L1I(1) L1I(2) L1I(3) L1I(4)
        #undef L1I
        #undef L1Q

        TANH4(h0[0]) TANH4(h0[1]) TANH4(h0[2]) TANH4(h0[3])
        TANH4(h0[4]) TANH4(h0[5]) TANH4(h0[6]) TANH4(h0[7])
        TANH4(h1[0]) TANH4(h1[1]) TANH4(h1[2]) TANH4(h1[3])
        TANH4(h1[4]) TANH4(h1[5]) TANH4(h1[6]) TANH4(h1[7])

        // ---- layer 2: 32 -> 32 (the 2048-FLOP core) ----
        float4 c0[8], c1[8];
        #define INITC(q) { float4 b = b2v[q]; c0[q] = b; c1[q] = b; }
        INITC(0) INITC(1) INITC(2) INITC(3) INITC(4) INITC(5) INITC(6) INITC(7)
        #undef INITC

        #define L2Q(row, q) { float4 w = w2v[(row) * 8 + (q)]; \
            c0[q] = ffma4(x0, w, c0[q]); c1[q] = ffma4(x1, w, c1[q]); }
        #define L2K(k4, comp, row) { const float x0 = h0[k4].comp; const float x1 = h1[k4].comp; \
            L2Q(row,0) L2Q(row,1) L2Q(row,2) L2Q(row,3) L2Q(row,4) L2Q(row,5) L2Q(row,6) L2Q(row,7) }
        L2K(0,x, 0) L2K(0,y, 1) L2K(0,z, 2) L2K(0,w, 3)
        L2K(1,x, 4) L2K(1,y, 5) L2K(1,z, 6) L2K(1,w, 7)
        L2K(2,x, 8) L2K(2,y, 9) L2K(2,z,10) L2K(2,w,11)
        L2K(3,x,12) L2K(3,y,13) L2K(3,z,14) L2K(3,w,15)
        L2K(4,x,16) L2K(4,y,17) L2K(4,z,18) L2K(4,w,19)
        L2K(5,x,20) L2K(5,y,21) L2K(5,z,22) L2K(5,w,23)
        L2K(6,x,24) L2K(6,y,25) L2K(6,z,26) L2K(6,w,27)
        L2K(7,x,28) L2K(7,y,29) L2K(7,z,30) L2K(7,w,31)
        #undef L2K
        #undef L2Q

        TANH4(c0[0]) TANH4(c0[1]) TANH4(c0[2]) TANH4(c0[3])
        TANH4(c0[4]) TANH4(c0[5]) TANH4(c0[6]) TANH4(c0[7])
        TANH4(c1[0]) TANH4(c1[1]) TANH4(c1[2]) TANH4(c1[3])
        TANH4(c1[4]) TANH4(c1[5]) TANH4(c1[6]) TANH4(c1[7])

        // ---- layer 3: 32 -> 1 ----
        float e0 = bias3, e1 = bias3;
        #define L3Q(q) { float4 w = w3v[q]; \
            e0 = fmaf(c0[q].x, w.x, e0); e0 = fmaf(c0[q].y, w.y, e0); \
            e0 = fmaf(c0[q].z, w.z, e0); e0 = fmaf(c0[q].w, w.w, e0); \
            e1 = fmaf(c1[q].x, w.x, e1); e1 = fmaf(c1[q].y, w.y, e1); \
            e1 = fmaf(c1[q].z, w.z, e1); e1 = fmaf(c1[q].w, w.w, e1); }
        L3Q(0) L3Q(1) L3Q(2) L3Q(3) L3Q(4) L3Q(5) L3Q(6) L3Q(7)
        #undef L3Q

        out[(size_t)s0 * NA + a] = e0;
        if (v1) out[(size_t)s1 * NA + a] = e1;
    }
}

extern "C" void kernel_launch(void* const* d_in, const int* in_sizes, int n_in,
                              void* d_out, int out_size, void* d_ws, size_t ws_size,
                              hipStream_t stream) {
    const float* g  = (const float*)d_in[0];
    const float* W1 = (const float*)d_in[1];
    const float* b1 = (const float*)d_in[2];
    const float* W2 = (const float*)d_in[3];
    const float* b2 = (const float*)d_in[4];
    const float* W3 = (const float*)d_in[5];
    const float* b3 = (const float*)d_in[6];
    float* out = (float*)d_out;
    mlp_per_atom<<<dim3(NA), dim3(256), 0, stream>>>(g, W1, b1, W2, b2, W3, b3, out);
}

// Round 5
// 179.501 us; speedup vs baseline: 13.1389x; 13.1389x over previous
//
#include <hip/hip_runtime.h>

#define NS_TOT 2000
#define NA 1000
#define NI 5
#define NH 32
#define SCHUNK 256                 // structs per block
#define NCHUNK 8                   // ceil(NS_TOT / SCHUNK)

// tanh(x) = 1 - 2/(exp(2x)+1). Saturates correctly; ~1e-6 abs err.
__device__ __forceinline__ float fast_tanh(float x) {
    float E = __expf(2.0f * x);
    float r = __builtin_amdgcn_rcpf(E + 1.0f);
    return fmaf(-2.0f, r, 1.0f);
}

// value-semantics fma: acc += s * w (componentwise)
__device__ __forceinline__ float4 ffma4(float s, float4 w, float4 acc) {
    acc.x = fmaf(s, w.x, acc.x);
    acc.y = fmaf(s, w.y, acc.y);
    acc.z = fmaf(s, w.z, acc.z);
    acc.w = fmaf(s, w.w, acc.w);
    return acc;
}

#define TANH4(v) { (v).x = fast_tanh((v).x); (v).y = fast_tanh((v).y); \
                   (v).z = fast_tanh((v).z); (v).w = fast_tanh((v).w); }

// R2-R4 lesson: the AMDGPU allocator treats __launch_bounds__ arg2 as a MIN
// waves/EU and then voluntarily targets HIGHER occupancy, spilling live
// accumulators to scratch (R4: 6.3 GB HBM of spill traffic, VALUBusy 4%).
// Fix: (a) straight-line kernel (no struct loop -> no LICM, short live
// ranges, peak live ~85 VGPR), (b) amdgpu_waves_per_eu(4,4) pins occupancy
// EXACTLY -> 128-VGPR budget, no incentive to shrink-and-spill, (c) weights
// read directly from global with wave-uniform addresses -> scalar loads
// (s_load + v_fmac v,s,v), eliminating the ~170us LDS-broadcast ceiling of
// the R3 structure entirely.
__global__ __attribute__((amdgpu_flat_work_group_size(256, 256),
                          amdgpu_waves_per_eu(4, 4)))
void mlp_straight(
    const float* __restrict__ g,
    const float* __restrict__ W1, const float* __restrict__ b1,
    const float* __restrict__ W2, const float* __restrict__ b2,
    const float* __restrict__ W3, const float* __restrict__ b3,
    float* __restrict__ out)
{
    const int bid   = blockIdx.x;          // bid = chunk*NA + araw
    const int araw  = bid % NA;
    const int chunk = bid / NA;
    // XCD swizzle: consecutive atoms (which share 64B lines of g/out) land on
    // the same XCD (hw maps bid%8 -> XCD round-robin). NA = 8 * 125.
    const int a = (araw >> 3) + 125 * (araw & 7);
    const int s = chunk * SCHUNK + (int)threadIdx.x;
    if (s >= NS_TOT) return;

    // Wave-uniform weight bases (a is uniform) -> scalar loads.
    const float4* w1v = (const float4*)(W1 + (size_t)a * NI * NH);  // 40 x float4
    const float4* b1v = (const float4*)(b1 + (size_t)a * NH);       //  8 x float4
    const float4* w2v = (const float4*)(W2 + (size_t)a * NH * NH);  // 256 x float4
    const float4* b2v = (const float4*)(b2 + (size_t)a * NH);       //  8 x float4
    const float4* w3v = (const float4*)(W3 + (size_t)a * NH);       //  8 x float4
    const float bias3 = b3[a];

    // Per-thread input gather (inherently scattered: stride 20KB between lanes).
    const float* gp = g + ((size_t)s * NA + a) * NI;
    const float x0g = gp[0], x1g = gp[1], x2g = gp[2], x3g = gp[3], x4g = gp[4];

    // ---- layer 1: 5 -> 32 ----
    float4 h[8];
    #define INITH(q) h[q] = b1v[q];
    INITH(0) INITH(1) INITH(2) INITH(3) INITH(4) INITH(5) INITH(6) INITH(7)
    #undef INITH
    #define L1Q(i, q) h[q] = ffma4(xi, w1v[(i) * 8 + (q)], h[q]);
    #define L1I(i, xv) { const float xi = (xv); \
        L1Q(i,0) L1Q(i,1) L1Q(i,2) L1Q(i,3) L1Q(i,4) L1Q(i,5) L1Q(i,6) L1Q(i,7) }
    L1I(0, x0g) L1I(1, x1g) L1I(2, x2g) L1I(3, x3g) L1I(4, x4g)
    #undef L1I
    #undef L1Q
    TANH4(h[0]) TANH4(h[1]) TANH4(h[2]) TANH4(h[3])
    TANH4(h[4]) TANH4(h[5]) TANH4(h[6]) TANH4(h[7])

    // ---- layer 2: 32 -> 32 ----
    float4 c[8];
    #define INITC(q) c[q] = b2v[q];
    INITC(0) INITC(1) INITC(2) INITC(3) INITC(4) INITC(5) INITC(6) INITC(7)
    #undef INITC
    #define L2Q(row, q) c[q] = ffma4(xk, w2v[(row) * 8 + (q)], c[q]);
    #define L2K(k4, comp, row) { const float xk = h[k4].comp; \
        L2Q(row,0) L2Q(row,1) L2Q(row,2) L2Q(row,3) L2Q(row,4) L2Q(row,5) L2Q(row,6) L2Q(row,7) }
    L2K(0,x, 0) L2K(0,y, 1) L2K(0,z, 2) L2K(0,w, 3)
    L2K(1,x, 4) L2K(1,y, 5) L2K(1,z, 6) L2K(1,w, 7)
    L2K(2,x, 8) L2K(2,y, 9) L2K(2,z,10) L2K(2,w,11)
    L2K(3,x,12) L2K(3,y,13) L2K(3,z,14) L2K(3,w,15)
    L2K(4,x,16) L2K(4,y,17) L2K(4,z,18) L2K(4,w,19)
    L2K(5,x,20) L2K(5,y,21) L2K(5,z,22) L2K(5,w,23)
    L2K(6,x,24) L2K(6,y,25) L2K(6,z,26) L2K(6,w,27)
    L2K(7,x,28) L2K(7,y,29) L2K(7,z,30) L2K(7,w,31)
    #undef L2K
    #undef L2Q
    TANH4(c[0]) TANH4(c[1]) TANH4(c[2]) TANH4(c[3])
    TANH4(c[4]) TANH4(c[5]) TANH4(c[6]) TANH4(c[7])

    // ---- layer 3: 32 -> 1 ----
    float e = bias3;
    #define L3Q(q) { float4 w = w3v[q]; \
        e = fmaf(c[q].x, w.x, e); e = fmaf(c[q].y, w.y, e); \
        e = fmaf(c[q].z, w.z, e); e = fmaf(c[q].w, w.w, e); }
    L3Q(0) L3Q(1) L3Q(2) L3Q(3) L3Q(4) L3Q(5) L3Q(6) L3Q(7)
    #undef L3Q

    out[(size_t)s * NA + a] = e;
}

extern "C" void kernel_launch(void* const* d_in, const int* in_sizes, int n_in,
                              void* d_out, int out_size, void* d_ws, size_t ws_size,
                              hipStream_t stream) {
    const float* g  = (const float*)d_in[0];
    const float* W1 = (const float*)d_in[1];
    const float* b1 = (const float*)d_in[2];
    const float* W2 = (const float*)d_in[3];
    const float* b2 = (const float*)d_in[4];
    const float* W3 = (const float*)d_in[5];
    const float* b3 = (const float*)d_in[6];
    float* out = (float*)d_out;
    mlp_straight<<<dim3(NA * NCHUNK), dim3(SCHUNK), 0, stream>>>(
        g, W1, b1, W2, b2, W3, b3, out);
}

// Round 6
// 139.964 us; speedup vs baseline: 16.8505x; 1.2825x over previous
//
#include <hip/hip_runtime.h>
#include <hip/hip_bf16.h>

#define NS_TOT 2000
#define NA 1000
#define NI 5
#define NH 32

typedef __attribute__((ext_vector_type(8)))  short short8;   // 8 bf16 = 4 VGPR
typedef __attribute__((ext_vector_type(16))) float f32x16;   // MFMA 32x32 acc

// tanh(x) = 1 - 2/(exp(2x)+1). Saturates correctly; ~1e-6 abs err.
__device__ __forceinline__ float fast_tanh(float x) {
    float E = __expf(2.0f * x);
    float r = __builtin_amdgcn_rcpf(E + 1.0f);
    return fmaf(-2.0f, r, 1.0f);
}

__device__ __forceinline__ float4 ffma4(float s, float4 w, float4 acc) {
    acc.x = fmaf(s, w.x, acc.x);
    acc.y = fmaf(s, w.y, acc.y);
    acc.z = fmaf(s, w.z, acc.z);
    acc.w = fmaf(s, w.w, acc.w);
    return acc;
}

#define TANH4(v) { (v).x = fast_tanh((v).x); (v).y = fast_tanh((v).y); \
                   (v).z = fast_tanh((v).z); (v).w = fast_tanh((v).w); }

__device__ __forceinline__ unsigned short f2bf_rne(float x) {
    unsigned u = __float_as_uint(x);
    unsigned r = u + 0x7FFFu + ((u >> 16) & 1u);
    return (unsigned short)(r >> 16);
}

// two f32 -> packed bf16x2 (hw v_cvt_pk_bf16_f32 via HIP API)
__device__ __forceinline__ unsigned pack2(float a, float b) {
    __hip_bfloat162 p = __float22bfloat162_rn(make_float2(a, b));
    unsigned u; __builtin_memcpy(&u, &p, 4); return u;
}

// One block per atom, 4 waves. Per iteration each wave does 64 structs:
// layer1+tanh per-lane (VALU, scalar weights), pack bf16, stage to
// wave-PRIVATE LDS region (DS in-order per wave -> no __syncthreads in loop),
// read back as MFMA B-fragments, 2x v_mfma_f32_32x32x16_bf16 per 32-struct
// tile (acc pre-init with b2 in C-layout), tanh on acc, layer3 dot in-lane +
// shfl_xor(32). R5 lesson kept: amdgpu_waves_per_eu(4,4) pins occupancy so
// the allocator doesn't shrink-and-spill.
__global__ __attribute__((amdgpu_flat_work_group_size(256, 256),
                          amdgpu_waves_per_eu(4, 4)))
void mlp_mfma(
    const float* __restrict__ g,
    const float* __restrict__ W1, const float* __restrict__ b1,
    const float* __restrict__ W2, const float* __restrict__ b2,
    const float* __restrict__ W3, const float* __restrict__ b3,
    float* __restrict__ out)
{
    const int araw = blockIdx.x;
    // XCD swizzle: consecutive atoms (sharing 64B lines of g/out) -> same XCD.
    const int a = (araw >> 3) + 125 * (araw & 7);   // NA = 8*125
    const int t = threadIdx.x;
    const int lane = t & 63, wid = t >> 6;
    const int l31 = lane & 31, half = lane >> 5;

    __shared__ __align__(16) unsigned short sW2T[NH * NH];   // W2^T bf16 [m][k]
    __shared__ __align__(16) float sB2[NH];
    __shared__ __align__(16) float sW3[NH];
    // per-wave h1 stage: 64 structs x 32 bf16, row stride 40 ushort (80 B)
    // to break the 64B-stride 2-bank pattern.
    __shared__ __align__(16) unsigned short sH[4][64 * 40];

    // ---- stage W2^T (bf16), b2, W3 ----
    for (int idx = t; idx < NH * NH; idx += 256) {
        const int i = idx >> 5, j = idx & 31;            // W2[i][j]
        sW2T[j * NH + i] = f2bf_rne(W2[(size_t)a * NH * NH + idx]);
    }
    if (t < NH) { sB2[t] = b2[a * NH + t]; sW3[t] = W3[a * NH + t]; }
    __syncthreads();

    // ---- persistent per-lane fragments (hoisted out of the loop) ----
    // A[m=l31][k=half*8+j] = W2[k][m]; kstep1 at k+16.
    const short8 af0 = __builtin_bit_cast(short8, *(const uint4*)(sW2T + l31 * NH + half * 8));
    const short8 af1 = __builtin_bit_cast(short8, *(const uint4*)(sW2T + l31 * NH + 16 + half * 8));
    // C-layout row m = (r&3) + 8*(r>>2) + 4*half -> element r = q-th float4's (r&3)
    const float4 b2q0 = ((const float4*)sB2)[0 + half];
    const float4 b2q1 = ((const float4*)sB2)[2 + half];
    const float4 b2q2 = ((const float4*)sB2)[4 + half];
    const float4 b2q3 = ((const float4*)sB2)[6 + half];
    const float4 w3q0 = ((const float4*)sW3)[0 + half];
    const float4 w3q1 = ((const float4*)sW3)[2 + half];
    const float4 w3q2 = ((const float4*)sW3)[4 + half];
    const float4 w3q3 = ((const float4*)sW3)[6 + half];
    const float bias3 = b3[a];

    // wave-uniform layer1 weight bases -> scalar loads (R5-proven path)
    const float4* w1v = (const float4*)(W1 + (size_t)a * NI * NH);
    const float4* b1v = (const float4*)(b1 + (size_t)a * NH);

    unsigned short* hrow = sH[wid];

    for (int it = 0; it < 8; ++it) {
        const int base = it * 256 + wid * 64;
        const int s = base + lane;
        const int sl = (s < NS_TOT) ? s : (NS_TOT - 1);  // tail: duplicate work

        const float* gp = g + ((size_t)sl * NA + a) * NI;
        const float x0g = gp[0], x1g = gp[1], x2g = gp[2], x3g = gp[3], x4g = gp[4];

        // ---- layer 1: 5 -> 32 (VALU, scalar weights) ----
        float4 h[8];
        #define INITH(q) h[q] = b1v[q];
        INITH(0) INITH(1) INITH(2) INITH(3) INITH(4) INITH(5) INITH(6) INITH(7)
        #undef INITH
        #define L1Q(i, q) h[q] = ffma4(xi, w1v[(i) * 8 + (q)], h[q]);
        #define L1I(i, xv) { const float xi = (xv); \
            L1Q(i,0) L1Q(i,1) L1Q(i,2) L1Q(i,3) L1Q(i,4) L1Q(i,5) L1Q(i,6) L1Q(i,7) }
        L1I(0, x0g) L1I(1, x1g) L1I(2, x2g) L1I(3, x3g) L1I(4, x4g)
        #undef L1I
        #undef L1Q
        TANH4(h[0]) TANH4(h[1]) TANH4(h[2]) TANH4(h[3])
        TANH4(h[4]) TANH4(h[5]) TANH4(h[6]) TANH4(h[7])

        // ---- pack bf16, stage to wave-private LDS [struct][k] ----
        uint4* wp = (uint4*)(hrow + lane * 40);
        wp[0] = make_uint4(pack2(h[0].x,h[0].y), pack2(h[0].z,h[0].w),
                           pack2(h[1].x,h[1].y), pack2(h[1].z,h[1].w));
        wp[1] = make_uint4(pack2(h[2].x,h[2].y), pack2(h[2].z,h[2].w),
                           pack2(h[3].x,h[3].y), pack2(h[3].z,h[3].w));
        wp[2] = make_uint4(pack2(h[4].x,h[4].y), pack2(h[4].z,h[4].w),
                           pack2(h[5].x,h[5].y), pack2(h[5].z,h[5].w));
        wp[3] = make_uint4(pack2(h[6].x,h[6].y), pack2(h[6].z,h[6].w),
                           pack2(h[7].x,h[7].y), pack2(h[7].z,h[7].w));
        __builtin_amdgcn_wave_barrier();   // keep compiler from reordering DS ops

        // ---- B-fragments + MFMA (2 tiles of 32 structs, K=32 in 2 steps) ----
        const unsigned short* rb = hrow + half * 8;
        const short8 b00 = __builtin_bit_cast(short8, *(const uint4*)(rb + l31 * 40));
        const short8 b01 = __builtin_bit_cast(short8, *(const uint4*)(rb + l31 * 40 + 16));
        const short8 b10 = __builtin_bit_cast(short8, *(const uint4*)(rb + (32 + l31) * 40));
        const short8 b11 = __builtin_bit_cast(short8, *(const uint4*)(rb + (32 + l31) * 40 + 16));

        f32x16 acc0 = {b2q0.x, b2q0.y, b2q0.z, b2q0.w,
                       b2q1.x, b2q1.y, b2q1.z, b2q1.w,
                       b2q2.x, b2q2.y, b2q2.z, b2q2.w,
                       b2q3.x, b2q3.y, b2q3.z, b2q3.w};
        f32x16 acc1 = acc0;
        acc0 = __builtin_amdgcn_mfma_f32_32x32x16_bf16(af0, b00, acc0, 0, 0, 0);
        acc0 = __builtin_amdgcn_mfma_f32_32x32x16_bf16(af1, b01, acc0, 0, 0, 0);
        acc1 = __builtin_amdgcn_mfma_f32_32x32x16_bf16(af0, b10, acc1, 0, 0, 0);
        acc1 = __builtin_amdgcn_mfma_f32_32x32x16_bf16(af1, b11, acc1, 0, 0, 0);

        // ---- tanh + layer 3 (16 m-rows per lane, partner holds other 16) ----
        float p0 = 0.f, p1 = 0.f;
        #define EP(r, wq, comp) { p0 = fmaf(fast_tanh(acc0[r]), (wq).comp, p0); \
                                  p1 = fmaf(fast_tanh(acc1[r]), (wq).comp, p1); }
        EP(0,w3q0,x) EP(1,w3q0,y) EP(2,w3q0,z) EP(3,w3q0,w)
        EP(4,w3q1,x) EP(5,w3q1,y) EP(6,w3q1,z) EP(7,w3q1,w)
        EP(8,w3q2,x) EP(9,w3q2,y) EP(10,w3q2,z) EP(11,w3q2,w)
        EP(12,w3q3,x) EP(13,w3q3,y) EP(14,w3q3,z) EP(15,w3q3,w)
        #undef EP
        p0 += __shfl_xor(p0, 32);
        p1 += __shfl_xor(p1, 32);

        if (lane < 32) {
            const int st0 = base + l31;
            const int st1 = base + 32 + l31;
            if (st0 < NS_TOT) out[(size_t)st0 * NA + a] = p0 + bias3;
            if (st1 < NS_TOT) out[(size_t)st1 * NA + a] = p1 + bias3;
        }
    }
}

extern "C" void kernel_launch(void* const* d_in, const int* in_sizes, int n_in,
                              void* d_out, int out_size, void* d_ws, size_t ws_size,
                              hipStream_t stream) {
    const float* g  = (const float*)d_in[0];
    const float* W1 = (const float*)d_in[1];
    const float* b1 = (const float*)d_in[2];
    const float* W2 = (const float*)d_in[3];
    const float* b2 = (const float*)d_in[4];
    const float* W3 = (const float*)d_in[5];
    const float* b3 = (const float*)d_in[6];
    float* out = (float*)d_out;
    mlp_mfma<<<dim3(NA), dim3(256), 0, stream>>>(g, W1, b1, W2, b2, W3, b3, out);
}